// Round 9
// baseline (184.612 us; speedup 1.0000x reference)
//
#include <hip/hip_runtime.h>

typedef __attribute__((ext_vector_type(8))) __bf16 bf16x8;
typedef __attribute__((ext_vector_type(4))) __bf16 bf16x4;
typedef __attribute__((ext_vector_type(4))) float  f32x4;

static constexpr int TSEQ    = 2048;
static constexpr int DMODEL  = 1024;
static constexpr int HD      = 64;
static constexpr int VSTRIDE = 2080;   // V^T row stride (breaks 4KB L2-channel aliasing)
static constexpr int LSTR    = 72;     // attn LDS row stride (36 dwords)

#define AS1 __attribute__((address_space(1)))
#define AS3 __attribute__((address_space(3)))

// ---------------- fused preprocessing: convert x + transpose weights ----------------
__global__ __launch_bounds__(256) void k_prep(const float* __restrict__ x,
    const float* __restrict__ w0, const float* __restrict__ w1,
    const float* __restrict__ w2, const float* __restrict__ w3,
    __bf16* __restrict__ xbf, __bf16* __restrict__ wt_all) {
  __shared__ float tile[32][33];
  const int blk = blockIdx.x;
  const int tid = threadIdx.x;
  if (blk < 4096) {
    size_t i = ((size_t)blk * 256 + tid) * 4;
    float4 v = *(const float4*)(x + i);
    bf16x4 o = { (__bf16)v.x, (__bf16)v.y, (__bf16)v.z, (__bf16)v.w };
    *(bf16x4*)(xbf + i) = o;
    return;
  }
  const int tz = blk - 4096;
  const int wi = tz >> 10;                 // which weight
  const int tl = tz & 1023;
  const int n0 = (tl & 31) * 32, k0 = (tl >> 5) * 32;
  const float* w = wi == 0 ? w0 : wi == 1 ? w1 : wi == 2 ? w2 : w3;
  __bf16* out = wt_all + (size_t)wi * DMODEL * DMODEL;
  const int tx = tid & 31, ty0 = (tid >> 5) * 4;
#pragma unroll
  for (int j = 0; j < 4; j++)
    tile[ty0 + j][tx] = w[(size_t)(k0 + ty0 + j) * DMODEL + n0 + tx];
  __syncthreads();
#pragma unroll
  for (int j = 0; j < 4; j++)
    out[(size_t)(n0 + ty0 + j) * DMODEL + k0 + tx] = (__bf16)tile[tx][ty0 + j];
}

// ---------------- GEMM mainloop R15: 3-buffer ring + counted vmcnt, UN-PINNED ----------
// R14 minus sched_barrier(0) (m141: order-pinning regresses) and minus lgkmcnt(0)
// (unnecessary: a wave reaches barrier k only after its step-(k-1) MFMAs, which the
// compiler gates on the ds_read lgkm counts -> its buf[(k-1)%3] reads are complete;
// stagers target buf[(k+1)%3] != buf[(k-1)%3], so the ring is collision-free).
// Counted vmcnt: batch k+1 issued at TOP of iter k, waited at top of iter k+1 ->
// a full iteration (~8 ds_read + 16 MFMA) of latency cover instead of 2-buf's ~80 cyc.
// Each wave's vmcnt covers its own quarter-tile; the barrier rendezvous covers the rest.
template <int NB>
__device__ __forceinline__ void gemm_mainloop_r(const __bf16* __restrict__ A,
                                                const __bf16* __restrict__ Bt,
                                                int bm, int bn,
                                                __bf16* At, __bf16* Bl,
                                                f32x4 acc[4][NB / 32]) {
  constexpr int NT = NB / 32;
  const int tid  = threadIdx.x;
  const int lane = tid & 63;
  const int l15  = lane & 15, quad = lane >> 4;
  const int wv   = tid >> 6;
  const int wm   = (wv >> 1) * 64, wn = (wv & 1) * (NT * 16);
  const int srow = lane >> 2;                                   // staging row in 16-row group
  const int scol = (((lane & 3) ^ ((lane >> 3) & 3)) << 3);     // pre-swizzled 16B chunk (elems)
  const int rsw  = (l15 >> 1) & 3;                              // read-side XOR term

  auto stage = [&](int k0, int rb) {
#pragma unroll
    for (int ss = 0; ss < 2; ss++) {
      const int s   = wv * 2 + ss;
      const int row = s * 16 + srow;
      __builtin_amdgcn_global_load_lds(
          (const AS1 void*)(A + (size_t)(bm + row) * 1024 + k0 + scol),
          (AS3 void*)(At + rb * 4096 + s * 512), 16, 0, 0);
    }
#pragma unroll
    for (int ss = 0; ss < NB / 64; ss++) {
      const int s   = wv * (NB / 64) + ss;
      const int row = s * 16 + srow;
      __builtin_amdgcn_global_load_lds(
          (const AS1 void*)(Bt + (size_t)(bn + row) * 1024 + k0 + scol),
          (AS3 void*)(Bl + rb * (NB * 32) + s * 512), 16, 0, 0);
    }
  };

  stage(0, 0);                            // prologue: tile 0 in flight
  int rb = 0;
  for (int k0 = 0; k0 < 1024; k0 += 32) {
    const int nrb = (rb == 2) ? 0 : rb + 1;
    if (k0 + 32 < 1024) {
      stage(k0 + 32, nrb);                // issue next tile FIRST (stays in flight)
      if constexpr (NB == 128) asm volatile("s_waitcnt vmcnt(4)" ::: "memory");
      else                     asm volatile("s_waitcnt vmcnt(3)" ::: "memory");
    } else {
      asm volatile("s_waitcnt vmcnt(0)" ::: "memory");
    }
    __builtin_amdgcn_s_barrier();         // all waves: tile k landed (per-wave vmcnt + rendezvous)
    bf16x8 af[4], bfr[NT];
#pragma unroll
    for (int mt = 0; mt < 4; mt++)
      af[mt] = *(const bf16x8*)(At + rb * 4096 + (wm + mt * 16 + l15) * 32 +
                                ((quad ^ rsw) << 3));
#pragma unroll
    for (int nt = 0; nt < NT; nt++)
      bfr[nt] = *(const bf16x8*)(Bl + rb * (NB * 32) + (wn + nt * 16 + l15) * 32 +
                                 ((quad ^ rsw) << 3));
#pragma unroll
    for (int mt = 0; mt < 4; mt++)
#pragma unroll
      for (int nt = 0; nt < NT; nt++)
        acc[mt][nt] = __builtin_amdgcn_mfma_f32_16x16x32_bf16(
            af[mt], bfr[nt], acc[mt][nt], 0, 0, 0);
    rb = nrb;
  }
}

// ---------------- QKV projection (Q pre-scaled by log2e/8; V stored transposed) ----------------
__global__ __launch_bounds__(256) void k_gemm_qkv(const __bf16* __restrict__ xbf,
    const __bf16* __restrict__ wt_all, __bf16* __restrict__ qws,
    __bf16* __restrict__ kws, __bf16* __restrict__ vtws) {
  __shared__ __bf16 At[3 * 128 * 32];
  __shared__ __bf16 Bl[3 * 128 * 32];
  const int which = blockIdx.z;
  const __bf16* wt = wt_all + (size_t)which * DMODEL * DMODEL;
  const int bm = blockIdx.y * 128, bn = blockIdx.x * 128;
  f32x4 acc[4][4];
  const f32x4 z = {0.f, 0.f, 0.f, 0.f};
#pragma unroll
  for (int mt = 0; mt < 4; mt++)
#pragma unroll
    for (int nt = 0; nt < 4; nt++) acc[mt][nt] = z;
  gemm_mainloop_r<128>(xbf, wt, bm, bn, At, Bl, acc);
  const int lane = threadIdx.x & 63;
  const int l15 = lane & 15, quad = lane >> 4;
  const int wv = threadIdx.x >> 6;
  const int wm = (wv >> 1) * 64, wn = (wv & 1) * 64;
  if (which == 2) {
    // V^T: r-axis (4 consecutive t) vectorized into one bf16x4 store
#pragma unroll
    for (int mt = 0; mt < 4; mt++)
#pragma unroll
      for (int nt = 0; nt < 4; nt++) {
        int t0 = bm + wm + mt * 16 + quad * 4;
        int n = bn + wn + nt * 16 + l15;
        int h = n >> 6, d = n & 63;
        int b = t0 >> 11;
        int bh = b * 16 + h;
        bf16x4 o = { (__bf16)acc[mt][nt][0], (__bf16)acc[mt][nt][1],
                     (__bf16)acc[mt][nt][2], (__bf16)acc[mt][nt][3] };
        *(bf16x4*)(vtws + ((size_t)bh * HD + d) * VSTRIDE + (t0 & 2047)) = o;
      }
  } else {
#pragma unroll
    for (int mt = 0; mt < 4; mt++)
#pragma unroll
      for (int nt = 0; nt < 4; nt++)
#pragma unroll
        for (int r = 0; r < 4; r++) {
          int m = bm + wm + mt * 16 + quad * 4 + r;
          int n = bn + wn + nt * 16 + l15;
          int b = m >> 11, t = m & 2047;
          int h = n >> 6,  d = n & 63;
          int bh = b * 16 + h;
          float av = acc[mt][nt][r];
          // 0.125 * log2(e): attention uses v_exp_f32 (exp2) directly
          if (which == 0) qws[((size_t)bh * TSEQ + t) * HD + d] = (__bf16)(av * 0.18033688f);
          else            kws[((size_t)bh * TSEQ + t) * HD + d] = (__bf16)av;
        }
  }
}

// ---------------- flash attention (R14 version, frozen; exp2 + P-chunk XOR swizzle) ----------------
__global__ __launch_bounds__(256) void k_attn(const __bf16* __restrict__ qws,
    const __bf16* __restrict__ kws, const __bf16* __restrict__ vtws,
    __bf16* __restrict__ ctx) {
  const int bh  = blockIdx.x & 31;
  const int qb0 = blockIdx.x >> 5, qb1 = 31 - qb0;
  const int tid = threadIdx.x;
  const int lane = tid & 63, wv = tid >> 6;
  const int l15 = lane & 15, quad = lane >> 4;
  const __bf16* qp = qws  + (size_t)bh * TSEQ * HD;
  const __bf16* kp = kws  + (size_t)bh * TSEQ * HD;
  const __bf16* vp = vtws + (size_t)bh * HD * VSTRIDE;
  const int b = bh >> 4, h = bh & 15;

  __shared__ __bf16 kbuf[2][64 * LSTR];
  __shared__ __bf16 vbuf[2][64 * LSTR];
  __shared__ __bf16 plds[4][16 * LSTR];

  const f32x4 z = {0.f, 0.f, 0.f, 0.f};
  const int sr = tid >> 3, sc = (tid & 7) * 8;

  const int qr0a = qb0 * 64 + wv * 16;
  const int qr0b = qb1 * 64 + wv * 16;
  bf16x8 aq0[2], aq1[2];
#pragma unroll
  for (int kb = 0; kb < 2; kb++) {
    aq0[kb] = *(const bf16x8*)(qp + (size_t)(qr0a + l15) * HD + kb * 32 + quad * 8);
    aq1[kb] = *(const bf16x8*)(qp + (size_t)(qr0b + l15) * HD + kb * 32 + quad * 8);
  }

  bf16x8 kreg[2], vreg[2];
  kreg[0] = *(const bf16x8*)(kp + (size_t)sr * HD + sc);
  kreg[1] = *(const bf16x8*)(kp + (size_t)(sr + 32) * HD + sc);
  vreg[0] = *(const bf16x8*)(vp + (size_t)sr * VSTRIDE + sc);
  vreg[1] = *(const bf16x8*)(vp + (size_t)(sr + 32) * VSTRIDE + sc);
  *(bf16x8*)(kbuf[0] + sr * LSTR + sc)        = kreg[0];
  *(bf16x8*)(kbuf[0] + (sr + 32) * LSTR + sc) = kreg[1];
  *(bf16x8*)(vbuf[0] + sr * LSTR + sc)        = vreg[0];
  *(bf16x8*)(vbuf[0] + (sr + 32) * LSTR + sc) = vreg[1];
  __syncthreads();

  float lpart[4] = {0.f, 0.f, 0.f, 0.f};
  f32x4 acc[4];
#pragma unroll
  for (int dt = 0; dt < 4; dt++) acc[dt] = z;

  for (int s = 0; s < 33; s++) {
    const int cur = s & 1;
    const bool h0 = (s <= qb0);
    const bool masked = (s == qb0) || (s == 32);

    if (s + 1 < 33) {
      const int ktn = (s + 1 <= qb0) ? (s + 1) * 64 : (s - qb0) * 64;
      kreg[0] = *(const bf16x8*)(kp + (size_t)(ktn + sr) * HD + sc);
      kreg[1] = *(const bf16x8*)(kp + (size_t)(ktn + sr + 32) * HD + sc);
      vreg[0] = *(const bf16x8*)(vp + (size_t)sr * VSTRIDE + ktn + sc);
      vreg[1] = *(const bf16x8*)(vp + (size_t)(sr + 32) * VSTRIDE + ktn + sc);
    }

    const __bf16* kb_ = kbuf[cur];
    const __bf16* vb_ = vbuf[cur];
    f32x4 sarr[4];
#pragma unroll
    for (int nt = 0; nt < 4; nt++) sarr[nt] = z;
#pragma unroll
    for (int nt = 0; nt < 4; nt++)
#pragma unroll
      for (int kb = 0; kb < 2; kb++) {
        bf16x8 bk = *(const bf16x8*)(kb_ + (nt * 16 + l15) * LSTR + kb * 32 + quad * 8);
        bf16x8 a  = h0 ? aq0[kb] : aq1[kb];
        sarr[nt] = __builtin_amdgcn_mfma_f32_16x16x32_bf16(a, bk, sarr[nt], 0, 0, 0);
      }
    if (masked) {
#pragma unroll
      for (int r = 0; r < 4; r++) {
        const int qloc = wv * 16 + quad * 4 + r;
#pragma unroll
        for (int nt = 0; nt < 4; nt++) {
          int kloc = nt * 16 + l15;
          float p = (kloc <= qloc) ? __builtin_amdgcn_exp2f(sarr[nt][r]) : 0.f;
          lpart[r] += p;
          plds[wv][(quad * 4 + r) * LSTR + ((nt ^ quad) * 16) + l15] = (__bf16)p;
        }
      }
    } else {
#pragma unroll
      for (int r = 0; r < 4; r++)
#pragma unroll
        for (int nt = 0; nt < 4; nt++) {
          float p = __builtin_amdgcn_exp2f(sarr[nt][r]);
          lpart[r] += p;
          plds[wv][(quad * 4 + r) * LSTR + ((nt ^ quad) * 16) + l15] = (__bf16)p;
        }
    }
#pragma unroll
    for (int kb = 0; kb < 2; kb++) {
      const int pch = (2 * kb + (quad >> 1)) ^ (l15 >> 2);
      bf16x8 ap = *(const bf16x8*)(&plds[wv][l15 * LSTR + pch * 16 + (quad & 1) * 8]);
#pragma unroll
      for (int dt = 0; dt < 4; dt++) {
        bf16x8 bvv = *(const bf16x8*)(vb_ + (dt * 16 + l15) * LSTR + kb * 32 + quad * 8);
        acc[dt] = __builtin_amdgcn_mfma_f32_16x16x32_bf16(ap, bvv, acc[dt], 0, 0, 0);
      }
    }

    if (s + 1 < 33) {
      const int nxt = cur ^ 1;
      *(bf16x8*)(kbuf[nxt] + sr * LSTR + sc)        = kreg[0];
      *(bf16x8*)(kbuf[nxt] + (sr + 32) * LSTR + sc) = kreg[1];
      *(bf16x8*)(vbuf[nxt] + sr * LSTR + sc)        = vreg[0];
      *(bf16x8*)(vbuf[nxt] + (sr + 32) * LSTR + sc) = vreg[1];
    }
    __syncthreads();

    if (masked) {
      const int qr0 = h0 ? qr0a : qr0b;
#pragma unroll
      for (int r = 0; r < 4; r++) {
        float l = lpart[r];
        l += __shfl_xor(l, 1, 64);
        l += __shfl_xor(l, 2, 64);
        l += __shfl_xor(l, 4, 64);
        l += __shfl_xor(l, 8, 64);
        float linv = 1.f / l;
        const int qrow = qr0 + quad * 4 + r;
#pragma unroll
        for (int dt = 0; dt < 4; dt++)
          ctx[((size_t)(b * TSEQ + qrow)) * DMODEL + h * 64 + dt * 16 + l15] =
              (__bf16)(acc[dt][r] * linv);
        lpart[r] = 0.f;
      }
#pragma unroll
      for (int dt = 0; dt < 4; dt++) acc[dt] = z;
    }
  }
}

// ---------------- output projection + bias (fp32 out); 128x64 tiles -> 512 blocks ----------------
__global__ __launch_bounds__(256) void k_gemm_out(const __bf16* __restrict__ ctx,
    const __bf16* __restrict__ wot, const float* __restrict__ bo,
    float* __restrict__ out) {
  __shared__ __bf16 At[3 * 128 * 32];
  __shared__ __bf16 Bl[3 * 64 * 32];
  const int bm = blockIdx.y * 128, bn = blockIdx.x * 64;
  f32x4 acc[4][2];
  const f32x4 z = {0.f, 0.f, 0.f, 0.f};
#pragma unroll
  for (int mt = 0; mt < 4; mt++)
#pragma unroll
    for (int nt = 0; nt < 2; nt++) acc[mt][nt] = z;
  gemm_mainloop_r<64>(ctx, wot, bm, bn, At, Bl, acc);
  const int lane = threadIdx.x & 63;
  const int l15 = lane & 15, quad = lane >> 4;
  const int wv = threadIdx.x >> 6;
  const int wm = (wv >> 1) * 64, wn = (wv & 1) * 32;
#pragma unroll
  for (int mt = 0; mt < 4; mt++)
#pragma unroll
    for (int nt = 0; nt < 2; nt++)
#pragma unroll
      for (int r = 0; r < 4; r++) {
        int m = bm + wm + mt * 16 + quad * 4 + r;
        int n = bn + wn + nt * 16 + l15;
        out[(size_t)m * DMODEL + n] = acc[mt][nt][r] + bo[n];
      }
}

extern "C" void kernel_launch(void* const* d_in, const int* in_sizes, int n_in,
                              void* d_out, int out_size, void* d_ws, size_t ws_size,
                              hipStream_t stream) {
  const float* x  = (const float*)d_in[0];
  const float* Wq = (const float*)d_in[1];
  const float* Wk = (const float*)d_in[2];
  const float* Wv = (const float*)d_in[3];
  const float* Wo = (const float*)d_in[4];
  const float* bo = (const float*)d_in[5];
  float* out = (float*)d_out;

  __bf16* xbf  = (__bf16*)d_ws;                       // 4096*1024
  __bf16* wt   = xbf  + (size_t)4096 * 1024;          // 4 * 1024*1024
  __bf16* qws  = wt   + (size_t)4 * 1024 * 1024;      // [32][2048][64]
  __bf16* kws  = qws  + (size_t)32 * 2048 * 64;
  __bf16* vtws = kws  + (size_t)32 * 2048 * 64;       // [32][64][VSTRIDE]
  __bf16* ctx  = xbf;                                 // aliases xbf (dead after QKV)

  k_prep<<<8192, 256, 0, stream>>>(x, Wq, Wk, Wv, Wo, xbf, wt);
  k_gemm_qkv<<<dim3(8, 32, 3), 256, 0, stream>>>(xbf, wt, qws, kws, vtws);
  k_attn<<<512, 256, 0, stream>>>(qws, kws, vtws, ctx);
  k_gemm_out<<<dim3(16, 32), 256, 0, stream>>>(ctx, wt + (size_t)3 * 1024 * 1024, bo, out);
}

// Round 10
// 173.437 us; speedup vs baseline: 1.0644x; 1.0644x over previous
//
#include <hip/hip_runtime.h>

typedef __attribute__((ext_vector_type(8))) __bf16 bf16x8;
typedef __attribute__((ext_vector_type(4))) __bf16 bf16x4;
typedef __attribute__((ext_vector_type(4))) float  f32x4;

static constexpr int TSEQ    = 2048;
static constexpr int DMODEL  = 1024;
static constexpr int HD      = 64;
static constexpr int VSTRIDE = 2080;   // V^T row stride (breaks 4KB L2-channel aliasing)
static constexpr int LSTR    = 72;     // attn LDS row stride (36 dwords)

#define AS1 __attribute__((address_space(1)))
#define AS3 __attribute__((address_space(3)))

// ---------------- fused preprocessing: convert x + transpose weights ----------------
__global__ __launch_bounds__(256) void k_prep(const float* __restrict__ x,
    const float* __restrict__ w0, const float* __restrict__ w1,
    const float* __restrict__ w2, const float* __restrict__ w3,
    __bf16* __restrict__ xbf, __bf16* __restrict__ wt_all) {
  __shared__ float tile[32][33];
  const int blk = blockIdx.x;
  const int tid = threadIdx.x;
  if (blk < 4096) {
    size_t i = ((size_t)blk * 256 + tid) * 4;
    float4 v = *(const float4*)(x + i);
    bf16x4 o = { (__bf16)v.x, (__bf16)v.y, (__bf16)v.z, (__bf16)v.w };
    *(bf16x4*)(xbf + i) = o;
    return;
  }
  const int tz = blk - 4096;
  const int wi = tz >> 10;                 // which weight
  const int tl = tz & 1023;
  const int n0 = (tl & 31) * 32, k0 = (tl >> 5) * 32;
  const float* w = wi == 0 ? w0 : wi == 1 ? w1 : wi == 2 ? w2 : w3;
  __bf16* out = wt_all + (size_t)wi * DMODEL * DMODEL;
  const int tx = tid & 31, ty0 = (tid >> 5) * 4;
#pragma unroll
  for (int j = 0; j < 4; j++)
    tile[ty0 + j][tx] = w[(size_t)(k0 + ty0 + j) * DMODEL + n0 + tx];
  __syncthreads();
#pragma unroll
  for (int j = 0; j < 4; j++)
    out[(size_t)(n0 + ty0 + j) * DMODEL + k0 + tx] = (__bf16)tile[tx][ty0 + j];
}

// ---------------- GEMM mainloop (R13, best measured): BK=32 dbuf + intra-line XOR swizzle --
// Swizzle chunk ^= (row>>1)&3 confined to one 64B line: global coalescing intact, b128
// fragment reads spread 2 lanes/bank-group = free floor. Single top-of-iter barrier.
template <int NB>
__device__ __forceinline__ void gemm_mainloop_p(const __bf16* __restrict__ A,
                                                const __bf16* __restrict__ Bt,
                                                int bm, int bn,
                                                __bf16* At, __bf16* Bl,
                                                f32x4 acc[4][NB / 32]) {
  constexpr int NT = NB / 32;
  const int tid  = threadIdx.x;
  const int lane = tid & 63;
  const int l15  = lane & 15, quad = lane >> 4;
  const int wv   = tid >> 6;
  const int wm   = (wv >> 1) * 64, wn = (wv & 1) * (NT * 16);
  const int srow = lane >> 2;                                   // staging row in 16-row group
  const int scol = (((lane & 3) ^ ((lane >> 3) & 3)) << 3);     // pre-swizzled 16B chunk (elems)
  const int rsw  = (l15 >> 1) & 3;                              // read-side XOR term

  auto stage = [&](int k0, int hb) {
#pragma unroll
    for (int ss = 0; ss < 2; ss++) {
      const int s   = wv * 2 + ss;
      const int row = s * 16 + srow;
      __builtin_amdgcn_global_load_lds(
          (const AS1 void*)(A + (size_t)(bm + row) * 1024 + k0 + scol),
          (AS3 void*)(At + hb * 4096 + s * 512), 16, 0, 0);
    }
#pragma unroll
    for (int ss = 0; ss < NB / 64; ss++) {
      const int s   = wv * (NB / 64) + ss;
      const int row = s * 16 + srow;
      __builtin_amdgcn_global_load_lds(
          (const AS1 void*)(Bt + (size_t)(bn + row) * 1024 + k0 + scol),
          (AS3 void*)(Bl + hb * (NB * 32) + s * 512), 16, 0, 0);
    }
  };

  stage(0, 0);                            // prologue
  for (int k0 = 0; k0 < 1024; k0 += 32) {
    const int cur = (k0 >> 5) & 1;
    __syncthreads();                      // tile k landed; prior reads of buf^1 done
    bf16x8 af[4], bfr[NT];
#pragma unroll
    for (int mt = 0; mt < 4; mt++)
      af[mt] = *(const bf16x8*)(At + cur * 4096 + (wm + mt * 16 + l15) * 32 +
                                ((quad ^ rsw) << 3));
#pragma unroll
    for (int nt = 0; nt < NT; nt++)
      bfr[nt] = *(const bf16x8*)(Bl + cur * (NB * 32) + (wn + nt * 16 + l15) * 32 +
                                 ((quad ^ rsw) << 3));
    if (k0 + 32 < 1024) stage(k0 + 32, cur ^ 1);   // overlap with MFMA below
#pragma unroll
    for (int mt = 0; mt < 4; mt++)
#pragma unroll
      for (int nt = 0; nt < NT; nt++)
        acc[mt][nt] = __builtin_amdgcn_mfma_f32_16x16x32_bf16(
            af[mt], bfr[nt], acc[mt][nt], 0, 0, 0);
  }
}

// ---------------- QKV projection, XCD-aware 2D remap (R16) ----------------
// Round-robin dispatch: XCD = blockIdx % 8. Old grid (8,32,3) gave XCD = n-block%8 ->
// every XCD streams the FULL 8MB A panel: FETCH 68.7MB (measured R12) vs 14MB ideal.
// Remap: xcd -> (mg,ng) = 8 m-blocks x 4 n-blocks x 3 weights; within-XCD m-fastest.
// Active set = 2MB A-panel + 256KB B-panel < 4MB L2. Chip fetch: A 4x2MBx2 + B 6MBx4
// = 40MB. 1D grid 768.
__global__ __launch_bounds__(256) void k_gemm_qkv(const __bf16* __restrict__ xbf,
    const __bf16* __restrict__ wt_all, __bf16* __restrict__ qws,
    __bf16* __restrict__ kws, __bf16* __restrict__ vtws) {
  __shared__ __bf16 At[2 * 128 * 32];
  __shared__ __bf16 Bl[2 * 128 * 32];
  const int id  = blockIdx.x;
  const int xcd = id & 7, idx = id >> 3;       // idx 0..95
  const int mg = xcd >> 1, ng = xcd & 1;       // 4 m-groups x 2 n-groups
  const int which = idx >> 5;                  // 3 weights
  const int rem = idx & 31;                    // 8m x 4n
  const int nn = rem >> 3, mm = rem & 7;       // m fastest
  const int bm = (mg * 8 + mm) * 128;
  const int bn = (ng * 4 + nn) * 128;
  const __bf16* wt = wt_all + (size_t)which * DMODEL * DMODEL;
  f32x4 acc[4][4];
  const f32x4 z = {0.f, 0.f, 0.f, 0.f};
#pragma unroll
  for (int mt = 0; mt < 4; mt++)
#pragma unroll
    for (int nt = 0; nt < 4; nt++) acc[mt][nt] = z;
  gemm_mainloop_p<128>(xbf, wt, bm, bn, At, Bl, acc);
  const int lane = threadIdx.x & 63;
  const int l15 = lane & 15, quad = lane >> 4;
  const int wv = threadIdx.x >> 6;
  const int wm = (wv >> 1) * 64, wn = (wv & 1) * 64;
  if (which == 2) {
    // V^T: r-axis (4 consecutive t) vectorized into one bf16x4 store
#pragma unroll
    for (int mt = 0; mt < 4; mt++)
#pragma unroll
      for (int nt = 0; nt < 4; nt++) {
        int t0 = bm + wm + mt * 16 + quad * 4;
        int n = bn + wn + nt * 16 + l15;
        int h = n >> 6, d = n & 63;
        int b = t0 >> 11;
        int bh = b * 16 + h;
        bf16x4 o = { (__bf16)acc[mt][nt][0], (__bf16)acc[mt][nt][1],
                     (__bf16)acc[mt][nt][2], (__bf16)acc[mt][nt][3] };
        *(bf16x4*)(vtws + ((size_t)bh * HD + d) * VSTRIDE + (t0 & 2047)) = o;
      }
  } else {
#pragma unroll
    for (int mt = 0; mt < 4; mt++)
#pragma unroll
      for (int nt = 0; nt < 4; nt++)
#pragma unroll
        for (int r = 0; r < 4; r++) {
          int m = bm + wm + mt * 16 + quad * 4 + r;
          int n = bn + wn + nt * 16 + l15;
          int b = m >> 11, t = m & 2047;
          int h = n >> 6,  d = n & 63;
          int bh = b * 16 + h;
          float av = acc[mt][nt][r];
          // 0.125 * log2(e): attention uses v_exp_f32 (exp2) directly
          if (which == 0) qws[((size_t)bh * TSEQ + t) * HD + d] = (__bf16)(av * 0.18033688f);
          else            kws[((size_t)bh * TSEQ + t) * HD + d] = (__bf16)av;
        }
  }
}

// ---------------- flash attention (frozen R14/R15 bytes; exp2 + P-chunk XOR swizzle) ----------------
__global__ __launch_bounds__(256) void k_attn(const __bf16* __restrict__ qws,
    const __bf16* __restrict__ kws, const __bf16* __restrict__ vtws,
    __bf16* __restrict__ ctx) {
  const int bh  = blockIdx.x & 31;
  const int qb0 = blockIdx.x >> 5, qb1 = 31 - qb0;
  const int tid = threadIdx.x;
  const int lane = tid & 63, wv = tid >> 6;
  const int l15 = lane & 15, quad = lane >> 4;
  const __bf16* qp = qws  + (size_t)bh * TSEQ * HD;
  const __bf16* kp = kws  + (size_t)bh * TSEQ * HD;
  const __bf16* vp = vtws + (size_t)bh * HD * VSTRIDE;
  const int b = bh >> 4, h = bh & 15;

  __shared__ __bf16 kbuf[2][64 * LSTR];
  __shared__ __bf16 vbuf[2][64 * LSTR];
  __shared__ __bf16 plds[4][16 * LSTR];

  const f32x4 z = {0.f, 0.f, 0.f, 0.f};
  const int sr = tid >> 3, sc = (tid & 7) * 8;

  const int qr0a = qb0 * 64 + wv * 16;
  const int qr0b = qb1 * 64 + wv * 16;
  bf16x8 aq0[2], aq1[2];
#pragma unroll
  for (int kb = 0; kb < 2; kb++) {
    aq0[kb] = *(const bf16x8*)(qp + (size_t)(qr0a + l15) * HD + kb * 32 + quad * 8);
    aq1[kb] = *(const bf16x8*)(qp + (size_t)(qr0b + l15) * HD + kb * 32 + quad * 8);
  }

  bf16x8 kreg[2], vreg[2];
  kreg[0] = *(const bf16x8*)(kp + (size_t)sr * HD + sc);
  kreg[1] = *(const bf16x8*)(kp + (size_t)(sr + 32) * HD + sc);
  vreg[0] = *(const bf16x8*)(vp + (size_t)sr * VSTRIDE + sc);
  vreg[1] = *(const bf16x8*)(vp + (size_t)(sr + 32) * VSTRIDE + sc);
  *(bf16x8*)(kbuf[0] + sr * LSTR + sc)        = kreg[0];
  *(bf16x8*)(kbuf[0] + (sr + 32) * LSTR + sc) = kreg[1];
  *(bf16x8*)(vbuf[0] + sr * LSTR + sc)        = vreg[0];
  *(bf16x8*)(vbuf[0] + (sr + 32) * LSTR + sc) = vreg[1];
  __syncthreads();

  float lpart[4] = {0.f, 0.f, 0.f, 0.f};
  f32x4 acc[4];
#pragma unroll
  for (int dt = 0; dt < 4; dt++) acc[dt] = z;

  for (int s = 0; s < 33; s++) {
    const int cur = s & 1;
    const bool h0 = (s <= qb0);
    const bool masked = (s == qb0) || (s == 32);

    if (s + 1 < 33) {
      const int ktn = (s + 1 <= qb0) ? (s + 1) * 64 : (s - qb0) * 64;
      kreg[0] = *(const bf16x8*)(kp + (size_t)(ktn + sr) * HD + sc);
      kreg[1] = *(const bf16x8*)(kp + (size_t)(ktn + sr + 32) * HD + sc);
      vreg[0] = *(const bf16x8*)(vp + (size_t)sr * VSTRIDE + ktn + sc);
      vreg[1] = *(const bf16x8*)(vp + (size_t)(sr + 32) * VSTRIDE + ktn + sc);
    }

    const __bf16* kb_ = kbuf[cur];
    const __bf16* vb_ = vbuf[cur];
    f32x4 sarr[4];
#pragma unroll
    for (int nt = 0; nt < 4; nt++) sarr[nt] = z;
#pragma unroll
    for (int nt = 0; nt < 4; nt++)
#pragma unroll
      for (int kb = 0; kb < 2; kb++) {
        bf16x8 bk = *(const bf16x8*)(kb_ + (nt * 16 + l15) * LSTR + kb * 32 + quad * 8);
        bf16x8 a  = h0 ? aq0[kb] : aq1[kb];
        sarr[nt] = __builtin_amdgcn_mfma_f32_16x16x32_bf16(a, bk, sarr[nt], 0, 0, 0);
      }
    if (masked) {
#pragma unroll
      for (int r = 0; r < 4; r++) {
        const int qloc = wv * 16 + quad * 4 + r;
#pragma unroll
        for (int nt = 0; nt < 4; nt++) {
          int kloc = nt * 16 + l15;
          float p = (kloc <= qloc) ? __builtin_amdgcn_exp2f(sarr[nt][r]) : 0.f;
          lpart[r] += p;
          plds[wv][(quad * 4 + r) * LSTR + ((nt ^ quad) * 16) + l15] = (__bf16)p;
        }
      }
    } else {
#pragma unroll
      for (int r = 0; r < 4; r++)
#pragma unroll
        for (int nt = 0; nt < 4; nt++) {
          float p = __builtin_amdgcn_exp2f(sarr[nt][r]);
          lpart[r] += p;
          plds[wv][(quad * 4 + r) * LSTR + ((nt ^ quad) * 16) + l15] = (__bf16)p;
        }
    }
#pragma unroll
    for (int kb = 0; kb < 2; kb++) {
      const int pch = (2 * kb + (quad >> 1)) ^ (l15 >> 2);
      bf16x8 ap = *(const bf16x8*)(&plds[wv][l15 * LSTR + pch * 16 + (quad & 1) * 8]);
#pragma unroll
      for (int dt = 0; dt < 4; dt++) {
        bf16x8 bvv = *(const bf16x8*)(vb_ + (dt * 16 + l15) * LSTR + kb * 32 + quad * 8);
        acc[dt] = __builtin_amdgcn_mfma_f32_16x16x32_bf16(ap, bvv, acc[dt], 0, 0, 0);
      }
    }

    if (s + 1 < 33) {
      const int nxt = cur ^ 1;
      *(bf16x8*)(kbuf[nxt] + sr * LSTR + sc)        = kreg[0];
      *(bf16x8*)(kbuf[nxt] + (sr + 32) * LSTR + sc) = kreg[1];
      *(bf16x8*)(vbuf[nxt] + sr * LSTR + sc)        = vreg[0];
      *(bf16x8*)(vbuf[nxt] + (sr + 32) * LSTR + sc) = vreg[1];
    }
    __syncthreads();

    if (masked) {
      const int qr0 = h0 ? qr0a : qr0b;
#pragma unroll
      for (int r = 0; r < 4; r++) {
        float l = lpart[r];
        l += __shfl_xor(l, 1, 64);
        l += __shfl_xor(l, 2, 64);
        l += __shfl_xor(l, 4, 64);
        l += __shfl_xor(l, 8, 64);
        float linv = 1.f / l;
        const int qrow = qr0 + quad * 4 + r;
#pragma unroll
        for (int dt = 0; dt < 4; dt++)
          ctx[((size_t)(b * TSEQ + qrow)) * DMODEL + h * 64 + dt * 16 + l15] =
              (__bf16)(acc[dt][r] * linv);
        lpart[r] = 0.f;
      }
#pragma unroll
      for (int dt = 0; dt < 4; dt++) acc[dt] = z;
    }
  }
}

// ---------------- output projection + bias, XCD-aware 2D remap (R16) ----------------
// Old grid (16,32): XCD = n-block%8 -> full 8MB ctx per XCD (~65MB chip). Remap:
// xcd -> 8 m-blocks x 8 n-blocks (64-wide); chip fetch ~ A 16MB + B 8MB = 24MB.
// 1D grid 512.
__global__ __launch_bounds__(256) void k_gemm_out(const __bf16* __restrict__ ctx,
    const __bf16* __restrict__ wot, const float* __restrict__ bo,
    float* __restrict__ out) {
  __shared__ __bf16 At[2 * 128 * 32];
  __shared__ __bf16 Bl[2 * 64 * 32];
  const int id  = blockIdx.x;
  const int xcd = id & 7, idx = id >> 3;       // idx 0..63
  const int mg = xcd >> 1, ng = xcd & 1;       // 4 m-groups x 2 n-groups
  const int nn = idx >> 3, mm = idx & 7;       // 8n x 8m, m fastest
  const int bm = (mg * 8 + mm) * 128;
  const int bn = (ng * 8 + nn) * 64;
  f32x4 acc[4][2];
  const f32x4 z = {0.f, 0.f, 0.f, 0.f};
#pragma unroll
  for (int mt = 0; mt < 4; mt++)
#pragma unroll
    for (int nt = 0; nt < 2; nt++) acc[mt][nt] = z;
  gemm_mainloop_p<64>(ctx, wot, bm, bn, At, Bl, acc);
  const int lane = threadIdx.x & 63;
  const int l15 = lane & 15, quad = lane >> 4;
  const int wv = threadIdx.x >> 6;
  const int wm = (wv >> 1) * 64, wn = (wv & 1) * 32;
#pragma unroll
  for (int mt = 0; mt < 4; mt++)
#pragma unroll
    for (int nt = 0; nt < 2; nt++)
#pragma unroll
      for (int r = 0; r < 4; r++) {
        int m = bm + wm + mt * 16 + quad * 4 + r;
        int n = bn + wn + nt * 16 + l15;
        out[(size_t)m * DMODEL + n] = acc[mt][nt][r] + bo[n];
      }
}

extern "C" void kernel_launch(void* const* d_in, const int* in_sizes, int n_in,
                              void* d_out, int out_size, void* d_ws, size_t ws_size,
                              hipStream_t stream) {
  const float* x  = (const float*)d_in[0];
  const float* Wq = (const float*)d_in[1];
  const float* Wk = (const float*)d_in[2];
  const float* Wv = (const float*)d_in[3];
  const float* Wo = (const float*)d_in[4];
  const float* bo = (const float*)d_in[5];
  float* out = (float*)d_out;

  __bf16* xbf  = (__bf16*)d_ws;                       // 4096*1024
  __bf16* wt   = xbf  + (size_t)4096 * 1024;          // 4 * 1024*1024
  __bf16* qws  = wt   + (size_t)4 * 1024 * 1024;      // [32][2048][64]
  __bf16* kws  = qws  + (size_t)32 * 2048 * 64;
  __bf16* vtws = kws  + (size_t)32 * 2048 * 64;       // [32][64][VSTRIDE]
  __bf16* ctx  = xbf;                                 // aliases xbf (dead after QKV)

  k_prep<<<8192, 256, 0, stream>>>(x, Wq, Wk, Wv, Wo, xbf, wt);
  k_gemm_qkv<<<768, 256, 0, stream>>>(xbf, wt, qws, kws, vtws);
  k_attn<<<512, 256, 0, stream>>>(qws, kws, vtws, ctx);
  k_gemm_out<<<512, 256, 0, stream>>>(ctx, wt + (size_t)3 * 1024 * 1024, bo, out);
}